// Round 1
// 381.116 us; speedup vs baseline: 1.0136x; 1.0136x over previous
//
#include <hip/hip_runtime.h>
#include <hip/hip_bf16.h>
#include <math.h>

#define N_PROTS 2048
#define N_MOLS  16384
#define DIM     768
#define SHIFT   16.0f
#define MARGIN  0.5f

typedef __attribute__((ext_vector_type(8))) short short8;
typedef __attribute__((ext_vector_type(4))) float f32x4;
typedef __attribute__((ext_vector_type(4))) unsigned short us4;
typedef __attribute__((ext_vector_type(8))) unsigned short us8;

__device__ __forceinline__ unsigned short bf16rnd(float x) {
    unsigned int u = __float_as_uint(x);
    u += 0x7fffu + ((u >> 16) & 1u);   // round-to-nearest-even
    return (unsigned short)(u >> 16);
}

__device__ __forceinline__ void gload16(const void* g, void* l) {
    __builtin_amdgcn_global_load_lds(
        (const __attribute__((address_space(1))) unsigned int*)g,
        (__attribute__((address_space(3))) unsigned int*)l, 16, 0, 0);
}

// ws layout:
//  floats [0, 34824): 0..2048 row_sumexp | 2048..18432 col_sumexp |
//                     18432..34816 pos_sim | 34816..34824 scalars
//  then 16B-aligned: protBf (2048*768 bf16, linear), molBf (16384*768 bf16, linear)
#define ACC_FLOATS 34824
#define PROT_BF_OFF_B 139296ull                      // 34824*4, 16B aligned
#define PROT_BF_BYTES (2048ull*768*2)
#define MOL_BF_OFF_B  (PROT_BF_OFF_B + PROT_BF_BYTES)
#define MOL_BF_BYTES  (16384ull*768*2)
#define WS_NEED       (MOL_BF_OFF_B + MOL_BF_BYTES)  // ~28.5 MB

// ---------------- one-shot fp32 -> bf16 conversion ----------------
__global__ __launch_bounds__(256)
void convert_bf16(const float* __restrict__ prot, const float* __restrict__ mol,
                  unsigned short* __restrict__ protBf, unsigned short* __restrict__ molBf)
{
    const size_t PROT_G = (size_t)N_PROTS * DIM / 8;   // 16B chunks
    size_t t = (size_t)blockIdx.x * 256 + threadIdx.x;
    const float* src;
    unsigned short* dst;
    if (t < PROT_G) { src = prot + t * 8; dst = protBf + t * 8; }
    else            { size_t u = t - PROT_G; src = mol + u * 8; dst = molBf + u * 8; }
    float4 v0 = ((const float4*)src)[0];
    float4 v1 = ((const float4*)src)[1];
    us8 o;
    o[0] = bf16rnd(v0.x); o[1] = bf16rnd(v0.y); o[2] = bf16rnd(v0.z); o[3] = bf16rnd(v0.w);
    o[4] = bf16rnd(v1.x); o[5] = bf16rnd(v1.y); o[6] = bf16rnd(v1.z); o[7] = bf16rnd(v1.w);
    *(us8*)dst = o;
}

// ---- bf16 GEMM v2: 256x256 tile, 8 waves, BK=32, 4-deep counted-vmcnt pipe ----
// Schedule: tile t lives in LDS slot t&3. While computing tile t (2 phases:
// mi 0..3 then mi 4..7), stage A(t+3) in phase0 and B(t+3) in phase1 into slot
// (t+3)&3 (== slot of t-1, whose reads all completed before this tile's
// barrier). Per tile: one s_waitcnt vmcnt(8) (tiles t+1,t+2 = 8 loads/thread
// stay in flight -- never drained to 0) + one raw s_barrier. 24 K-tiles.
// LDS: 4 slots x (A 16KB + B 16KB) = 128KB -> 1 block/CU, 8 waves (2/SIMD).
// Swizzle: LDS chunk slot cs of row r holds global 16B-chunk cs^(r&3); read
// side uses slot q^(l15&3) -> uniform 8 lanes per 4-bank quad, conflict-free
// (same construction as the previous verified kernel, re-derived for BK=32).
__global__ __launch_bounds__(512, 2)
void sim_pass_bf16_v2(const unsigned short* __restrict__ protBf,
                      const unsigned short* __restrict__ molBf,
                      const float* __restrict__ scale_p,
                      float* __restrict__ row_se, float* __restrict__ col_se,
                      float* __restrict__ pos_sim, float* __restrict__ scalars)
{
    __shared__ unsigned short As[4][256][32];   // 64 KB
    __shared__ unsigned short Bs[4][256][32];   // 64 KB
    __shared__ float redBuf[8];

    const int tid = threadIdx.x;
    // XCD-aware bijective swizzle: grid 512, nwg%8==0.
    const int bid  = blockIdx.x;
    const int xcd  = bid & 7;
    const int sl8  = bid >> 3;                 // 0..63
    const int bx   = xcd * 8 + (sl8 & 7);      // 0..63  (col tile)
    const int by   = sl8 >> 3;                 // 0..7   (row tile)
    const int rowBase = by * 256;
    const int colBase = bx * 256;

    const int wave = tid >> 6;
    const int lane = tid & 63;
    const int wm = wave >> 2;                  // 0..1  -> 128-row half
    const int wn = wave & 3;                   // 0..3  -> 64-col slice
    const int l15 = lane & 15;
    const int q   = lane >> 4;

    // ---- staging addresses (per-thread, pre-swizzled global source) ----
    const int rsub = lane >> 2;                // 0..15 row within 16-row group
    const int cs   = lane & 3;                 // LDS chunk slot
    const int swz  = (cs ^ (rsub & 3)) << 3;   // halfword offset of source chunk
    const unsigned short* aP =
        protBf + (size_t)(rowBase + wave * 32 + rsub) * DIM + swz;
    const unsigned short* bP =
        molBf  + (size_t)(colBase + wave * 32 + rsub) * DIM + swz;

#define STAGE_A(sl, kt) do { \
    gload16(aP + (size_t)(kt) * 32,                    &As[sl][wave * 32][0]);      \
    gload16(aP + (size_t)(kt) * 32 + (size_t)16 * DIM, &As[sl][wave * 32 + 16][0]); \
} while (0)
#define STAGE_B(sl, kt) do { \
    gload16(bP + (size_t)(kt) * 32,                    &Bs[sl][wave * 32][0]);      \
    gload16(bP + (size_t)(kt) * 32 + (size_t)16 * DIM, &Bs[sl][wave * 32 + 16][0]); \
} while (0)

    f32x4 acc[8][4];
#pragma unroll
    for (int i = 0; i < 8; ++i)
#pragma unroll
        for (int j = 0; j < 4; ++j) acc[i][j] = (f32x4){0.f, 0.f, 0.f, 0.f};

    // ---- prologue: stage tiles 0,1,2 (12 loads/thread) ----
    STAGE_A(0, 0); STAGE_B(0, 0);
    STAGE_A(1, 1); STAGE_B(1, 1);
    STAGE_A(2, 2); STAGE_B(2, 2);

    // fragment read geometry
    const int fArow = wm * 128 + l15;          // + mi*16
    const int fBrow = wn * 64 + l15;           // + ni*16
    const int fsw   = (q ^ (l15 & 3)) << 3;    // halfword offset (16B aligned)

#pragma unroll 1
    for (int t = 0; t < 24; ++t) {
        const int sl   = t & 3;
        const int pf   = (t + 3) & 3;
        const int kpre = (t < 21) ? (t + 3) : (t - 5);   // dummy re-stage at tail
        // counted vmcnt: tiles t+1,t+2 (8 loads) stay in flight
        asm volatile("s_waitcnt vmcnt(8)" ::: "memory");
        __builtin_amdgcn_s_barrier();

        short8 aF[4], bF[4];
        // ---- phase 0: mi 0..3 ----
#pragma unroll
        for (int ni = 0; ni < 4; ++ni)
            bF[ni] = *(const short8*)&Bs[sl][fBrow + ni * 16][fsw];
#pragma unroll
        for (int mi = 0; mi < 4; ++mi)
            aF[mi] = *(const short8*)&As[sl][fArow + mi * 16][fsw];
        STAGE_A(pf, kpre);
        __builtin_amdgcn_s_setprio(1);
#pragma unroll
        for (int mi = 0; mi < 4; ++mi)
#pragma unroll
            for (int ni = 0; ni < 4; ++ni)
                acc[mi][ni] = __builtin_amdgcn_mfma_f32_16x16x32_bf16(
                    aF[mi], bF[ni], acc[mi][ni], 0, 0, 0);
        __builtin_amdgcn_s_setprio(0);

        // ---- phase 1: mi 4..7 (bF reused from registers) ----
#pragma unroll
        for (int mi = 0; mi < 4; ++mi)
            aF[mi] = *(const short8*)&As[sl][fArow + 64 + mi * 16][fsw];
        STAGE_B(pf, kpre);
        __builtin_amdgcn_s_setprio(1);
#pragma unroll
        for (int mi = 0; mi < 4; ++mi)
#pragma unroll
            for (int ni = 0; ni < 4; ++ni)
                acc[4 + mi][ni] = __builtin_amdgcn_mfma_f32_16x16x32_bf16(
                    aF[mi], bF[ni], acc[4 + mi][ni], 0, 0, 0);
        __builtin_amdgcn_s_setprio(0);
    }
#undef STAGE_A
#undef STAGE_B

    // ---------------- epilogue ----------------
    const float scale = scale_p[0];
    float csum[4] = {0.f, 0.f, 0.f, 0.f};
    float rl = 0.f;
#pragma unroll
    for (int mi = 0; mi < 8; ++mi) {
        float rs[4] = {0.f, 0.f, 0.f, 0.f};
#pragma unroll
        for (int ni = 0; ni < 4; ++ni) {
#pragma unroll
            for (int r = 0; r < 4; ++r) {
                float sim = acc[mi][ni][r] * scale;
                float e = __expf(sim - SHIFT);
                rs[r] += e;
                csum[ni] += e;
                rl += fmaxf(sim, 0.f);
                int rg = rowBase + wm * 128 + mi * 16 + q * 4 + r;
                int cg = colBase + wn * 64 + ni * 16 + l15;
                if ((cg >> 3) == rg) pos_sim[cg] = sim;   // unique writer
            }
        }
#pragma unroll
        for (int r = 0; r < 4; ++r) {
            float v = rs[r];
            v += __shfl_xor(v, 1); v += __shfl_xor(v, 2);
            v += __shfl_xor(v, 4); v += __shfl_xor(v, 8);
            if (l15 == 0)
                atomicAdd(&row_se[rowBase + wm * 128 + mi * 16 + q * 4 + r], v);
        }
    }
#pragma unroll
    for (int ni = 0; ni < 4; ++ni) {
        float v = csum[ni];
        v += __shfl_xor(v, 16); v += __shfl_xor(v, 32);
        if (q == 0)
            atomicAdd(&col_se[colBase + wn * 64 + ni * 16 + l15], v);
    }
#pragma unroll
    for (int m = 1; m < 64; m <<= 1) rl += __shfl_xor(rl, m);
    if (lane == 0) redBuf[wave] = rl;
    __syncthreads();
    if (tid == 0) {
        float s = 0.f;
#pragma unroll
        for (int w = 0; w < 8; ++w) s += redBuf[w];
        atomicAdd(&scalars[0], s);
    }
}

// ---------------- fallback: fp32-staging GEMM (R1 kernel, known-good) --------
__global__ __launch_bounds__(256, 2)
void sim_pass(const float* __restrict__ prot, const float* __restrict__ mol,
              const float* __restrict__ scale_p,
              float* __restrict__ row_se, float* __restrict__ col_se,
              float* __restrict__ pos_sim, float* __restrict__ scalars)
{
    __shared__ unsigned short As[128][32];
    __shared__ unsigned short Bs[128][32];
    __shared__ float redBuf[4];

    const int tid = threadIdx.x;
    const int rowBase = blockIdx.y * 128;
    const int colBase = blockIdx.x * 128;
    const int wave = tid >> 6;
    const int lane = tid & 63;
    const int wr = (wave >> 1) * 64;
    const int wc = (wave & 1) * 64;
    const int l15 = lane & 15;
    const int q   = lane >> 4;

    f32x4 acc[4][4];
#pragma unroll
    for (int i = 0; i < 4; ++i)
#pragma unroll
        for (int j = 0; j < 4; ++j) acc[i][j] = (f32x4){0.f, 0.f, 0.f, 0.f};

    const float* aBase = prot + (size_t)rowBase * DIM;
    const float* bBase = mol  + (size_t)colBase * DIM;
    float4 aReg[4], bReg[4];
#pragma unroll
    for (int i = 0; i < 4; ++i) {
        int f = tid + 256 * i;
        int row = f >> 3, c4 = f & 7;
        aReg[i] = *(const float4*)(aBase + (size_t)row * DIM + (c4 << 2));
        bReg[i] = *(const float4*)(bBase + (size_t)row * DIM + (c4 << 2));
    }
#pragma unroll 1
    for (int s = 0; s < DIM / 32; ++s) {
#pragma unroll
        for (int i = 0; i < 4; ++i) {
            int f = tid + 256 * i;
            int row = f >> 3, c4 = f & 7;
            us4 av, bv;
            av.x = bf16rnd(aReg[i].x); av.y = bf16rnd(aReg[i].y);
            av.z = bf16rnd(aReg[i].z); av.w = bf16rnd(aReg[i].w);
            bv.x = bf16rnd(bReg[i].x); bv.y = bf16rnd(bReg[i].y);
            bv.z = bf16rnd(bReg[i].z); bv.w = bf16rnd(bReg[i].w);
            *(us4*)&As[row][c4 << 2] = av;
            *(us4*)&Bs[row][c4 << 2] = bv;
        }
        __syncthreads();
        if (s + 1 < DIM / 32) {
            int k0 = (s + 1) * 32;
#pragma unroll
            for (int i = 0; i < 4; ++i) {
                int f = tid + 256 * i;
                int row = f >> 3, c4 = f & 7;
                aReg[i] = *(const float4*)(aBase + (size_t)row * DIM + k0 + (c4 << 2));
                bReg[i] = *(const float4*)(bBase + (size_t)row * DIM + k0 + (c4 << 2));
            }
        }
        short8 aF[4], bF[4];
#pragma unroll
        for (int mi = 0; mi < 4; ++mi) aF[mi] = *(const short8*)&As[wr + mi * 16 + l15][q * 8];
#pragma unroll
        for (int ni = 0; ni < 4; ++ni) bF[ni] = *(const short8*)&Bs[wc + ni * 16 + l15][q * 8];
#pragma unroll
        for (int mi = 0; mi < 4; ++mi)
#pragma unroll
            for (int ni = 0; ni < 4; ++ni)
                acc[mi][ni] = __builtin_amdgcn_mfma_f32_16x16x32_bf16(aF[mi], bF[ni], acc[mi][ni], 0, 0, 0);
        __syncthreads();
    }

    const float scale = scale_p[0];
    float rsum[4][4];
    float csum[4] = {0.f, 0.f, 0.f, 0.f};
    float rl = 0.f;
#pragma unroll
    for (int mi = 0; mi < 4; ++mi)
#pragma unroll
        for (int r = 0; r < 4; ++r) rsum[mi][r] = 0.f;
#pragma unroll
    for (int mi = 0; mi < 4; ++mi) {
#pragma unroll
        for (int ni = 0; ni < 4; ++ni) {
#pragma unroll
            for (int r = 0; r < 4; ++r) {
                float sim = acc[mi][ni][r] * scale;
                float e = __expf(sim - SHIFT);
                rsum[mi][r] += e;
                csum[ni] += e;
                rl += fmaxf(sim, 0.f);
                int rg = rowBase + wr + mi * 16 + q * 4 + r;
                int cg = colBase + wc + ni * 16 + l15;
                if ((cg >> 3) == rg) pos_sim[cg] = sim;
            }
        }
    }
#pragma unroll
    for (int mi = 0; mi < 4; ++mi) {
#pragma unroll
        for (int r = 0; r < 4; ++r) {
            float v = rsum[mi][r];
            v += __shfl_xor(v, 1); v += __shfl_xor(v, 2);
            v += __shfl_xor(v, 4); v += __shfl_xor(v, 8);
            if (l15 == 0)
                atomicAdd(&row_se[rowBase + wr + mi * 16 + q * 4 + r], v);
        }
    }
#pragma unroll
    for (int ni = 0; ni < 4; ++ni) {
        float v = csum[ni];
        v += __shfl_xor(v, 16); v += __shfl_xor(v, 32);
        if (q == 0)
            atomicAdd(&col_se[colBase + wc + ni * 16 + l15], v);
    }
#pragma unroll
    for (int m = 1; m < 64; m <<= 1) rl += __shfl_xor(rl, m);
    if (lane == 0) redBuf[wave] = rl;
    __syncthreads();
    if (tid == 0)
        atomicAdd(&scalars[0], redBuf[0] + redBuf[1] + redBuf[2] + redBuf[3]);
}

// ---------------- finalize ----------------
__global__ __launch_bounds__(256)
void finalize1(const float* __restrict__ row_se, const float* __restrict__ col_se,
               const float* __restrict__ pos_sim, const float* __restrict__ pic50,
               float* __restrict__ scalars)
{
    int j = blockIdx.x * 256 + threadIdx.x;   // mol index
    float m2p = SHIFT + __logf(col_se[j]) - pos_sim[j];

    float p2m = 0.f, rank = 0.f, prelu = 0.f;
    if ((j & 7) == 0) {
        int i = j >> 3;
        float s[8], pc[8], pr[8];
#pragma unroll
        for (int p = 0; p < 8; ++p) {
            s[p]  = pos_sim[j + p];
            pr[p] = pic50[(size_t)i * N_MOLS + j + p];
            float x = (pr[p] - 2.0f) * 0.125f;
            pc[p] = fminf(fmaxf(x, 0.f), 1.f);
            prelu += fmaxf(s[p], 0.f);
        }
        float wsum = 1e-8f;
#pragma unroll
        for (int p = 0; p < 8; ++p) wsum += pc[p];
        float lse = SHIFT + __logf(row_se[i]);
        float accp = 0.f;
#pragma unroll
        for (int p = 0; p < 8; ++p) accp += pc[p] * (lse - s[p]);
        p2m = accp / wsum;
#pragma unroll
        for (int a = 0; a < 8; ++a)
#pragma unroll
            for (int b = a + 1; b < 8; ++b) {
                float dp = pr[a] - pr[b];
                float ds = s[a] - s[b];
                float v = (dp > 0.f) ? fmaxf(MARGIN - ds, 0.f)
                        : ((dp < 0.f) ? fmaxf(MARGIN + ds, 0.f) : 0.f);
                rank += v;
            }
    }

#pragma unroll
    for (int m = 1; m < 64; m <<= 1) {
        m2p   += __shfl_xor(m2p, m);
        p2m   += __shfl_xor(p2m, m);
        rank  += __shfl_xor(rank, m);
        prelu += __shfl_xor(prelu, m);
    }
    __shared__ float rbuf[4][4];
    int wave = threadIdx.x >> 6, lane = threadIdx.x & 63;
    if (lane == 0) { rbuf[wave][0] = m2p; rbuf[wave][1] = p2m; rbuf[wave][2] = rank; rbuf[wave][3] = prelu; }
    __syncthreads();
    if (threadIdx.x == 0) {
        float a = 0, b = 0, c = 0, d = 0;
        for (int w = 0; w < 4; ++w) { a += rbuf[w][0]; b += rbuf[w][1]; c += rbuf[w][2]; d += rbuf[w][3]; }
        atomicAdd(&scalars[2], a);
        atomicAdd(&scalars[1], b);
        atomicAdd(&scalars[3], c);
        atomicAdd(&scalars[4], d);
    }
}

__global__ void finalize2(const float* __restrict__ scalars, float* __restrict__ out)
{
    float relu_neg = scalars[0] - scalars[4];
    float p2m  = scalars[1] / (float)N_PROTS;
    float m2p  = scalars[2] / (float)N_MOLS;
    float rank = scalars[3] / ((float)N_PROTS * 28.0f);
    float neg  = relu_neg / ((float)N_PROTS * (float)N_MOLS);
    out[0] = p2m + m2p + 0.5f * rank + 0.1f * neg;
    out[1] = p2m;
    out[2] = m2p;
    out[3] = rank;
    out[4] = neg;
}

extern "C" void kernel_launch(void* const* d_in, const int* in_sizes, int n_in,
                              void* d_out, int out_size, void* d_ws, size_t ws_size,
                              hipStream_t stream) {
    const float* prot   = (const float*)d_in[0];
    const float* mol    = (const float*)d_in[1];
    const float* pic50  = (const float*)d_in[3];
    const float* lscale = (const float*)d_in[4];

    float* ws      = (float*)d_ws;
    float* row_se  = ws;
    float* col_se  = ws + 2048;
    float* pos_sim = ws + 2048 + 16384;
    float* scalars = ws + 2048 + 16384 + 16384;

    hipMemsetAsync(d_ws, 0, (size_t)ACC_FLOATS * sizeof(float), stream);

    if (ws_size >= WS_NEED) {
        unsigned short* protBf = (unsigned short*)((char*)d_ws + PROT_BF_OFF_B);
        unsigned short* molBf  = (unsigned short*)((char*)d_ws + MOL_BF_OFF_B);
        size_t groups = ((size_t)N_PROTS + N_MOLS) * DIM / 8;   // 1,769,472
        convert_bf16<<<(unsigned)(groups / 256), 256, 0, stream>>>(prot, mol, protBf, molBf);
        sim_pass_bf16_v2<<<512, 512, 0, stream>>>(protBf, molBf, lscale, row_se, col_se, pos_sim, scalars);
    } else {
        dim3 grid(N_MOLS / 128, N_PROTS / 128);
        sim_pass<<<grid, 256, 0, stream>>>(prot, mol, lscale, row_se, col_se, pos_sim, scalars);
    }
    finalize1<<<N_MOLS / 256, 256, 0, stream>>>(row_se, col_se, pos_sim, pic50, scalars);
    finalize2<<<1, 1, 0, stream>>>(scalars, (float*)d_out);
}